// Round 5
// baseline (11366.502 us; speedup 1.0000x reference)
//
#include <hip/hip_runtime.h>

// RSSM scan: B=512, T=64, STOCH=32, DETER=1024, HIDDEN=1024, ACT=12, EMBED=1536
// out: [2, 512, 64, 1120] f32  (post/prior; [mean(32), std(32), stoch(32), deter(1024)])

typedef __attribute__((ext_vector_type(8))) short short8;   // 8 x bf16 MFMA frag
typedef __attribute__((ext_vector_type(4))) float f32x4;    // MFMA accumulator

__device__ __forceinline__ unsigned short f2bf(float f) {
  union { float f; unsigned int u; } x; x.f = f;
  unsigned int r = x.u + 0x7fffu + ((x.u >> 16) & 1u);  // RNE
  return (unsigned short)(r >> 16);
}

// ---------------- prep: transpose+convert weights to bf16 W^T[N][Kpad] ----------------
__global__ __launch_bounds__(256) void prep_wT_k(
    const float* w0, const float* w1, const float* w2, const float* w3,
    const float* w4, const float* w5,
    unsigned short* o0, unsigned short* o1, unsigned short* o2,
    unsigned short* o3, unsigned short* o4, unsigned short* o5)
{
  long g = (long)blockIdx.x * 256 + threadIdx.x;
  const long n0 = 65536;             // w_inp:  K=44->64, N=1024
  const long n1 = n0 + 6291456;      // w_gru:  K=2048, N=3072
  const long n2 = n1 + 1048576;      // w_img:  K=1024, N=1024
  const long n3 = n2 + 2621440;      // w_obs:  K=2560, N=1024
  const long n4 = n3 + 65536;        // w_ims_stat: K=1024, N=64
  const long n5 = n4 + 65536;        // w_obs_stat: K=1024, N=64
  const float* src; unsigned short* dst; int K; int Kpad; int N; long loc;
  if      (g < n0) { src = w0; dst = o0; loc = g;      K = 44;   Kpad = 64;   N = 1024; }
  else if (g < n1) { src = w1; dst = o1; loc = g - n0; K = 2048; Kpad = 2048; N = 3072; }
  else if (g < n2) { src = w2; dst = o2; loc = g - n1; K = 1024; Kpad = 1024; N = 1024; }
  else if (g < n3) { src = w3; dst = o3; loc = g - n2; K = 2560; Kpad = 2560; N = 1024; }
  else if (g < n4) { src = w4; dst = o4; loc = g - n3; K = 1024; Kpad = 1024; N = 64; }
  else if (g < n5) { src = w5; dst = o5; loc = g - n4; K = 1024; Kpad = 1024; N = 64; }
  else return;
  long n = loc / Kpad;
  long k = loc % Kpad;
  float v = 0.f;
  if (k < K) v = src[k * (long)N + n];
  dst[loc] = f2bf(v);
}

// ---------------- prep: za_all[t][b][64] = [stoch(0), action, pad0]; zero deter ----------------
__global__ __launch_bounds__(256) void prep_state_k(
    const float* action, unsigned short* za, float* deter, unsigned short* deter_bf)
{
  long g = (long)blockIdx.x * 256 + threadIdx.x;
  if (g < 2097152) {             // 64*512*64
    long t = g >> 15;            // /(512*64)
    long r = g & 32767;
    long b = r >> 6;
    int c = (int)(r & 63);
    float v = 0.f;
    if (c >= 32 && c < 44) v = action[(b * 64 + t) * 12 + (c - 32)];
    za[g] = f2bf(v);
  } else {
    long i = g - 2097152;
    if (i < 524288) deter[i] = 0.f;
    else { i -= 524288; if (i < 524288) deter_bf[i] = 0; }
  }
}

// ---------------- generic 64x64-tile MFMA GEMM ----------------
// C[M x N] = concat_K(A1[M,K1] bf16, A2[M,K2] bf16-or-f32) * BT[N,K]^T + bias
// grid = (M/64, N/64). epilogue: elu? then write f32 (outF) or bf16 (outB).
__global__ __launch_bounds__(256) void gemm64_k(
    const unsigned short* __restrict__ A1, int lda1, int K1,
    const float* __restrict__ A2f, const unsigned short* __restrict__ A2b,
    int lda2, int K2,
    const unsigned short* __restrict__ BT, int ldbt,
    const float* __restrict__ bias,
    float* __restrict__ outF, unsigned short* __restrict__ outB, int ldo,
    int elu)
{
  __shared__ unsigned short As[64][72];
  __shared__ unsigned short Bs[64][72];

  const int tid = threadIdx.x;
  const int r = tid >> 3;
  const int c8 = (tid & 7) << 3;
  const int lane = tid & 63;
  const int wid = tid >> 6;
  const int wr = wid >> 1;
  const int wc = wid & 1;
  const int l16 = lane & 15;
  const int lq = lane >> 4;
  const int bm = blockIdx.x;
  const int bn = blockIdx.y;
  const int K = K1 + K2;

  f32x4 acc00 = {0.f, 0.f, 0.f, 0.f};
  f32x4 acc01 = {0.f, 0.f, 0.f, 0.f};
  f32x4 acc10 = {0.f, 0.f, 0.f, 0.f};
  f32x4 acc11 = {0.f, 0.f, 0.f, 0.f};

  for (int k0 = 0; k0 < K; k0 += 64) {
    for (int h = 0; h < 2; ++h) {
      int row = r + h * 32;
      int kk = k0 + c8;
      short8 av;
      if (kk < K1) {
        av = *(const short8*)(A1 + (size_t)(bm * 64 + row) * lda1 + kk);
      } else if (A2f) {
        const float* s = A2f + (size_t)(bm * 64 + row) * lda2 + (kk - K1);
        f32x4 f0 = *(const f32x4*)s;
        f32x4 f1 = *(const f32x4*)(s + 4);
        short8 t;
        t[0] = (short)f2bf(f0[0]); t[1] = (short)f2bf(f0[1]);
        t[2] = (short)f2bf(f0[2]); t[3] = (short)f2bf(f0[3]);
        t[4] = (short)f2bf(f1[0]); t[5] = (short)f2bf(f1[1]);
        t[6] = (short)f2bf(f1[2]); t[7] = (short)f2bf(f1[3]);
        av = t;
      } else {
        av = *(const short8*)(A2b + (size_t)(bm * 64 + row) * lda2 + (kk - K1));
      }
      *(short8*)&As[row][c8] = av;
      short8 bv = *(const short8*)(BT + (size_t)(bn * 64 + row) * ldbt + kk);
      *(short8*)&Bs[row][c8] = bv;
    }
    __syncthreads();
    for (int kk = 0; kk < 64; kk += 32) {
      short8 a0 = *(const short8*)&As[wr * 32 + l16][kk + lq * 8];
      short8 a1 = *(const short8*)&As[wr * 32 + 16 + l16][kk + lq * 8];
      short8 b0 = *(const short8*)&Bs[wc * 32 + l16][kk + lq * 8];
      short8 b1 = *(const short8*)&Bs[wc * 32 + 16 + l16][kk + lq * 8];
      acc00 = __builtin_amdgcn_mfma_f32_16x16x32_bf16(a0, b0, acc00, 0, 0, 0);
      acc01 = __builtin_amdgcn_mfma_f32_16x16x32_bf16(a0, b1, acc01, 0, 0, 0);
      acc10 = __builtin_amdgcn_mfma_f32_16x16x32_bf16(a1, b0, acc10, 0, 0, 0);
      acc11 = __builtin_amdgcn_mfma_f32_16x16x32_bf16(a1, b1, acc11, 0, 0, 0);
    }
    __syncthreads();
  }

  for (int mf = 0; mf < 2; ++mf) {
    for (int nf = 0; nf < 2; ++nf) {
      f32x4 a;
      if (mf == 0 && nf == 0) a = acc00;
      else if (mf == 0 && nf == 1) a = acc01;
      else if (mf == 1 && nf == 0) a = acc10;
      else a = acc11;
      int gc = bn * 64 + wc * 32 + nf * 16 + l16;
      float bv = bias[gc];
      for (int j = 0; j < 4; ++j) {
        int gr = bm * 64 + wr * 32 + mf * 16 + lq * 4 + j;
        float v = a[j] + bv;
        if (elu) v = v > 0.f ? v : expm1f(v);
        if (outF) outF[(size_t)gr * ldo + gc] = v;
        if (outB) outB[(size_t)gr * ldo + gc] = f2bf(v);
      }
    }
  }
}

// ---------------- GRU gates + deter output write ----------------
__global__ __launch_bounds__(256) void gates_k(
    const float* __restrict__ parts, float* __restrict__ deter,
    unsigned short* __restrict__ deter_bf, float* __restrict__ out, int t)
{
  int g = blockIdx.x * 256 + threadIdx.x;       // 512*1024 threads
  int b = g >> 10;
  int n = g & 1023;
  const float* pr = parts + (size_t)b * 3072;
  float reset = 1.f / (1.f + expf(-pr[n]));
  float cand  = tanhf(reset * pr[1024 + n]);
  float up    = 1.f / (1.f + expf(-(pr[2048 + n] - 1.f)));  // update_bias = -1
  float dn = up * cand + (1.f - up) * deter[g];
  deter[g] = dn;
  deter_bf[g] = f2bf(dn);
  out[((size_t)b * 64 + t) * 1120 + 96 + n] = dn;                  // post half
  out[((size_t)(512 + b) * 64 + t) * 1120 + 96 + n] = dn;          // prior half
}

// ---------------- stats GEMM (M=512 tiles, N=64, K=1024) + softplus/sample fused ----------------
__global__ __launch_bounds__(256) void stats_k(
    const unsigned short* __restrict__ A,    // [512][1024] bf16
    const unsigned short* __restrict__ BT,   // [64][1024] bf16
    const float* __restrict__ bias,          // [64]
    const float* __restrict__ eps,           // [512][32] (already offset by t)
    float* __restrict__ outbase,             // d_out + s*512*64*1120
    unsigned short* __restrict__ za_next,    // za + (t+1)*512*64 or null
    int t)
{
  __shared__ unsigned short As[64][72];
  __shared__ unsigned short Bs[64][72];
  __shared__ float Cs[64][65];

  const int tid = threadIdx.x;
  const int r = tid >> 3;
  const int c8 = (tid & 7) << 3;
  const int lane = tid & 63;
  const int wid = tid >> 6;
  const int wr = wid >> 1;
  const int wc = wid & 1;
  const int l16 = lane & 15;
  const int lq = lane >> 4;
  const int bm = blockIdx.x;

  f32x4 acc00 = {0.f, 0.f, 0.f, 0.f};
  f32x4 acc01 = {0.f, 0.f, 0.f, 0.f};
  f32x4 acc10 = {0.f, 0.f, 0.f, 0.f};
  f32x4 acc11 = {0.f, 0.f, 0.f, 0.f};

  for (int k0 = 0; k0 < 1024; k0 += 64) {
    for (int h = 0; h < 2; ++h) {
      int row = r + h * 32;
      int kk = k0 + c8;
      *(short8*)&As[row][c8] = *(const short8*)(A + (size_t)(bm * 64 + row) * 1024 + kk);
      *(short8*)&Bs[row][c8] = *(const short8*)(BT + (size_t)row * 1024 + kk);
    }
    __syncthreads();
    for (int kk = 0; kk < 64; kk += 32) {
      short8 a0 = *(const short8*)&As[wr * 32 + l16][kk + lq * 8];
      short8 a1 = *(const short8*)&As[wr * 32 + 16 + l16][kk + lq * 8];
      short8 b0 = *(const short8*)&Bs[wc * 32 + l16][kk + lq * 8];
      short8 b1 = *(const short8*)&Bs[wc * 32 + 16 + l16][kk + lq * 8];
      acc00 = __builtin_amdgcn_mfma_f32_16x16x32_bf16(a0, b0, acc00, 0, 0, 0);
      acc01 = __builtin_amdgcn_mfma_f32_16x16x32_bf16(a0, b1, acc01, 0, 0, 0);
      acc10 = __builtin_amdgcn_mfma_f32_16x16x32_bf16(a1, b0, acc10, 0, 0, 0);
      acc11 = __builtin_amdgcn_mfma_f32_16x16x32_bf16(a1, b1, acc11, 0, 0, 0);
    }
    __syncthreads();
  }

  for (int mf = 0; mf < 2; ++mf) {
    for (int nf = 0; nf < 2; ++nf) {
      f32x4 a;
      if (mf == 0 && nf == 0) a = acc00;
      else if (mf == 0 && nf == 1) a = acc01;
      else if (mf == 1 && nf == 0) a = acc10;
      else a = acc11;
      for (int j = 0; j < 4; ++j)
        Cs[wr * 32 + mf * 16 + lq * 4 + j][wc * 32 + nf * 16 + l16] = a[j];
    }
  }
  __syncthreads();

  int c = tid & 31;
  int r0 = (tid >> 5) * 8;
  for (int i = 0; i < 8; ++i) {
    int rr = r0 + i;
    int b = bm * 64 + rr;
    float mean = Cs[rr][c] + bias[c];
    float sraw = Cs[rr][c + 32] + bias[c + 32];
    float sp = sraw > 20.f ? sraw : log1pf(expf(sraw));
    float stddev = sp + 0.1f;
    float st = mean + stddev * eps[(size_t)b * 32 + c];
    float* ob = outbase + ((size_t)b * 64 + t) * 1120;
    ob[c] = mean;
    ob[32 + c] = stddev;
    ob[64 + c] = st;
    if (za_next) za_next[(size_t)b * 64 + c] = f2bf(st);
  }
}

// ---------------- launch ----------------
extern "C" void kernel_launch(void* const* d_in, const int* in_sizes, int n_in,
                              void* d_out, int out_size, void* d_ws, size_t ws_size,
                              hipStream_t stream) {
  (void)in_sizes; (void)n_in; (void)out_size; (void)ws_size;
  const float* embed      = (const float*)d_in[0];
  const float* action     = (const float*)d_in[1];
  const float* eps_prior  = (const float*)d_in[2];
  const float* eps_post   = (const float*)d_in[3];
  const float* w_inp      = (const float*)d_in[4];
  const float* b_inp      = (const float*)d_in[5];
  const float* w_gru      = (const float*)d_in[6];
  const float* b_gru      = (const float*)d_in[7];
  const float* w_img      = (const float*)d_in[8];
  const float* b_img      = (const float*)d_in[9];
  const float* w_obs      = (const float*)d_in[10];
  const float* b_obs      = (const float*)d_in[11];
  const float* w_ims_stat = (const float*)d_in[12];
  const float* b_ims_stat = (const float*)d_in[13];
  const float* w_obs_stat = (const float*)d_in[14];
  const float* b_obs_stat = (const float*)d_in[15];
  float* out = (float*)d_out;

  char* ws = (char*)d_ws;
  unsigned short* wT_inp = (unsigned short*)ws; ws += (size_t)1024 * 64 * 2;
  unsigned short* wT_gru = (unsigned short*)ws; ws += (size_t)3072 * 2048 * 2;
  unsigned short* wT_img = (unsigned short*)ws; ws += (size_t)1024 * 1024 * 2;
  unsigned short* wT_obs = (unsigned short*)ws; ws += (size_t)1024 * 2560 * 2;
  unsigned short* wT_ims = (unsigned short*)ws; ws += (size_t)64 * 1024 * 2;
  unsigned short* wT_ost = (unsigned short*)ws; ws += (size_t)64 * 1024 * 2;
  unsigned short* za     = (unsigned short*)ws; ws += (size_t)64 * 512 * 64 * 2;
  unsigned short* x_bf   = (unsigned short*)ws; ws += (size_t)512 * 1024 * 2;
  unsigned short* deter_bf = (unsigned short*)ws; ws += (size_t)512 * 1024 * 2;
  float* deter_f = (float*)ws; ws += (size_t)512 * 1024 * 4;
  float* parts   = (float*)ws; ws += (size_t)512 * 3072 * 4;
  unsigned short* h_bf  = (unsigned short*)ws; ws += (size_t)512 * 1024 * 2;
  unsigned short* ho_bf = (unsigned short*)ws; ws += (size_t)512 * 1024 * 2;

  prep_wT_k<<<39680, 256, 0, stream>>>(w_inp, w_gru, w_img, w_obs, w_ims_stat, w_obs_stat,
                                       wT_inp, wT_gru, wT_img, wT_obs, wT_ims, wT_ost);
  prep_state_k<<<12288, 256, 0, stream>>>(action, za, deter_f, deter_bf);

  for (int t = 0; t < 64; ++t) {
    // x = elu([stoch, act] @ w_inp + b_inp)  -> x_bf [512][1024]
    gemm64_k<<<dim3(8, 16), 256, 0, stream>>>(
        za + (size_t)t * 32768, 64, 64,
        nullptr, nullptr, 0, 0,
        wT_inp, 64, b_inp,
        nullptr, x_bf, 1024, 1);
    // parts = [x, deter] @ w_gru + b_gru  -> f32 [512][3072]
    gemm64_k<<<dim3(8, 48), 256, 0, stream>>>(
        x_bf, 1024, 1024,
        nullptr, deter_bf, 1024, 1024,
        wT_gru, 2048, b_gru,
        parts, nullptr, 3072, 0);
    // GRU gates -> deter_new (writes deter cols of both output halves)
    gates_k<<<2048, 256, 0, stream>>>(parts, deter_f, deter_bf, out, t);
    // h = elu(deter @ w_img + b_img) -> h_bf
    gemm64_k<<<dim3(8, 16), 256, 0, stream>>>(
        deter_bf, 1024, 1024,
        nullptr, nullptr, 0, 0,
        wT_img, 1024, b_img,
        nullptr, h_bf, 1024, 1);
    // ho = elu([deter, embed_t] @ w_obs + b_obs) -> ho_bf
    gemm64_k<<<dim3(8, 16), 256, 0, stream>>>(
        deter_bf, 1024, 1024,
        embed + (size_t)t * 1536, nullptr, 98304, 1536,
        wT_obs, 2560, b_obs,
        nullptr, ho_bf, 1024, 1);
    // prior stats (second half of out)
    stats_k<<<8, 256, 0, stream>>>(
        h_bf, wT_ims, b_ims_stat, eps_prior + (size_t)t * 16384,
        out + (size_t)512 * 64 * 1120, nullptr, t);
    // post stats (first half of out) + stoch carry into za[t+1]
    stats_k<<<8, 256, 0, stream>>>(
        ho_bf, wT_ost, b_obs_stat, eps_post + (size_t)t * 16384,
        out, (t < 63) ? (za + (size_t)(t + 1) * 32768) : nullptr, t);
  }
}